// Round 5
// baseline (77.614 us; speedup 1.0000x reference)
//
#include <hip/hip_runtime.h>

// score[b] = (sum_src[b] . sum_tar[b]) / (cnt_src[b] * cnt_tar[b])
// batch_src / batch_tar are SORTED -> segment b owns row range
// [lower_bound(b), lower_bound(b+1)) in each array. One block per segment:
// no atomics, no workspace, single launch. Src and tar streams interleaved
// with independent accumulators for deeper memory-level parallelism.
// All loop addressing is INDEXED (base + r*step), no pointer mutation --
// the R4 tail bug was a double-advanced pointer.

#define DIM  256
#define NSEG 512
#define NW   16          // waves per block
#define NT   (NW * 64)   // 1024 threads

// Cooperative 64-ary lower_bound: all 64 lanes probe, ballot picks the
// sub-range. Window shrinks ~64x/round: 200000 -> ~3126 -> ~50 -> ~2 -> 1.
__device__ __forceinline__ int lower_bound64(const int* __restrict__ a, int n,
                                             int key, int lane) {
    int LO = -1;   // invariant: a[LO] < key   (a[-1] = -inf)
    int HI = n;    // invariant: a[HI] >= key  (a[n]  = +inf)
    while (HI - LO > 1) {
        const int w   = HI - LO;
        const int pos = LO + 1 + (int)(((long long)(w - 1) * lane) >> 6);
        const bool pred = a[pos] < key;
        const unsigned long long mask = __ballot(pred);
        if (mask == 0ull) { HI = LO + 1; break; }
        const int kmax = 63 - __clzll(mask);
        const int nLO  = LO + 1 + (int)(((long long)(w - 1) * kmax) >> 6);
        const int nHI  = (kmax < 63)
                       ? (LO + 1 + (int)(((long long)(w - 1) * (kmax + 1)) >> 6))
                       : HI;
        LO = nLO; HI = nHI;
    }
    return HI;
}

__device__ __forceinline__ void acc4(float4& a, const float4 v) {
    a.x += v.x; a.y += v.y; a.z += v.z; a.w += v.w;
}

__device__ __forceinline__ float4 ld4(const float* p) {
    return *reinterpret_cast<const float4*>(p);
}

__global__ __launch_bounds__(NT) void fused_score_kernel(
    const float* __restrict__ x_src, const int* __restrict__ batch_src, int n_src,
    const float* __restrict__ x_tar, const int* __restrict__ batch_tar, int n_tar,
    float* __restrict__ out)
{
    __shared__ int   bounds[4];
    __shared__ float red[NW][DIM];   // 16 KB

    const int seg  = blockIdx.x;
    const int tid  = threadIdx.x;
    const int lane = tid & 63;
    const int w    = tid >> 6;       // wave id 0..15

    // waves 0..3 each find one boundary
    if (w < 4) {
        const int* arr = (w < 2) ? batch_src : batch_tar;
        const int  n   = (w < 2) ? n_src : n_tar;
        const int  lb  = lower_bound64(arr, n, seg + (w & 1), lane);
        if (lane == 0) bounds[w] = lb;
    }
    __syncthreads();
    const int s0 = bounds[0], s1 = bounds[1];
    const int t0 = bounds[2], t1 = bounds[3];

    // this wave's row counts (rows s0+w, s0+w+NW, ...)
    int cs = (s1 - s0 - w + NW - 1) / NW; if (cs < 0) cs = 0;
    int ct = (t1 - t0 - w + NW - 1) / NW; if (ct < 0) ct = 0;
    const int m = cs < ct ? cs : ct;

    const size_t step = (size_t)NW * DIM;
    const float* ps = x_src + (size_t)(s0 + w) * DIM + lane * 4;
    const float* pt = x_tar + (size_t)(t0 + w) * DIM + lane * 4;

    float4 aS0 = make_float4(0.f, 0.f, 0.f, 0.f);
    float4 aS1 = make_float4(0.f, 0.f, 0.f, 0.f);
    float4 aT0 = make_float4(0.f, 0.f, 0.f, 0.f);
    float4 aT1 = make_float4(0.f, 0.f, 0.f, 0.f);

    // interleaved dual-stream, 2x unroll: 4 independent loads in flight
    int r = 0;
    for (; r + 2 <= m; r += 2) {
        const float4 vs0 = ld4(ps + (size_t)r * step);
        const float4 vt0 = ld4(pt + (size_t)r * step);
        const float4 vs1 = ld4(ps + (size_t)(r + 1) * step);
        const float4 vt1 = ld4(pt + (size_t)(r + 1) * step);
        acc4(aS0, vs0); acc4(aT0, vt0); acc4(aS1, vs1); acc4(aT1, vt1);
    }
    if (r < m) {
        acc4(aS0, ld4(ps + (size_t)r * step));
        acc4(aT0, ld4(pt + (size_t)r * step));
        ++r;
    }
    // src tail
    {
        int rs = r;
        for (; rs + 2 <= cs; rs += 2) {
            const float4 v0 = ld4(ps + (size_t)rs * step);
            const float4 v1 = ld4(ps + (size_t)(rs + 1) * step);
            acc4(aS0, v0); acc4(aS1, v1);
        }
        if (rs < cs) acc4(aS0, ld4(ps + (size_t)rs * step));
    }
    // tar tail
    {
        int rt = r;
        for (; rt + 2 <= ct; rt += 2) {
            const float4 v0 = ld4(pt + (size_t)rt * step);
            const float4 v1 = ld4(pt + (size_t)(rt + 1) * step);
            acc4(aT0, v0); acc4(aT1, v1);
        }
        if (rt < ct) acc4(aT0, ld4(pt + (size_t)rt * step));
    }

    acc4(aS0, aS1);
    acc4(aT0, aT1);

    // cross-wave reduce src sums
    *reinterpret_cast<float4*>(&red[w][lane * 4]) = aS0;
    __syncthreads();
    float sumS = 0.f, sumT = 0.f;
    if (tid < DIM) {
        #pragma unroll
        for (int k = 0; k < NW; ++k) sumS += red[k][tid];
    }
    __syncthreads();

    // cross-wave reduce tar sums (reuse LDS)
    *reinterpret_cast<float4*>(&red[w][lane * 4]) = aT0;
    __syncthreads();
    if (tid < DIM) {
        #pragma unroll
        for (int k = 0; k < NW; ++k) sumT += red[k][tid];
        red[0][tid] = sumS * sumT;   // per-column products
    }
    __syncthreads();

    // wave 0: reduce 256 products -> dot, scale by 1/(cnt_src*cnt_tar)
    if (w == 0) {
        float d = red[0][lane] + red[0][lane + 64]
                + red[0][lane + 128] + red[0][lane + 192];
        #pragma unroll
        for (int off = 32; off > 0; off >>= 1)
            d += __shfl_down(d, off, 64);
        if (lane == 0) {
            const float c = (float)(s1 - s0) * (float)(t1 - t0);
            out[seg] = d / c;
        }
    }
}

extern "C" void kernel_launch(void* const* d_in, const int* in_sizes, int n_in,
                              void* d_out, int out_size, void* d_ws, size_t ws_size,
                              hipStream_t stream) {
    const float* x_src = (const float*)d_in[0];
    const int*   b_src = (const int*)  d_in[1];
    const float* x_tar = (const float*)d_in[2];
    const int*   b_tar = (const int*)  d_in[3];
    const int n_src = in_sizes[1];
    const int n_tar = in_sizes[3];
    float* out = (float*)d_out;

    fused_score_kernel<<<NSEG, NT, 0, stream>>>(
        x_src, b_src, n_src, x_tar, b_tar, n_tar, out);
}

// Round 6
// 74.516 us; speedup vs baseline: 1.0416x; 1.0416x over previous
//
#include <hip/hip_runtime.h>

// score[b] = (sum_src[b] . sum_tar[b]) / (cnt_src[b] * cnt_tar[b])
// batch_src / batch_tar are SORTED -> segment b owns row range
// [lower_bound(b), lower_bound(b+1)) in each array. One block per segment:
// no atomics, no workspace, no zero kernel, single launch.
//
// R5 post-mortem: interleaved dual-stream + manual unroll REGRESSED
// (74.5 -> 77.6 us, VGPR 24->32). At 32 waves/CU, TLP already saturates
// the read path; extra ILP only costs address VALU + registers. This is
// the R3 structure (best measured: 74.5 us = ~92% of the 6.29 TB/s
// stream ceiling after launch overhead). Remaining gap is the static
// per-CU segment-size imbalance tail (~4.5 us), which any dynamic
// rebalance scheme repays in extra launches + atomics.

#define DIM  256
#define NSEG 512
#define NW   16          // waves per block
#define NT   (NW * 64)   // 1024 threads

// Cooperative 64-ary lower_bound: all 64 lanes probe, ballot picks the
// sub-range. Window shrinks ~64x/round: 200000 -> ~3126 -> ~50 -> ~2 -> 1.
__device__ __forceinline__ int lower_bound64(const int* __restrict__ a, int n,
                                             int key, int lane) {
    int LO = -1;   // invariant: a[LO] < key   (a[-1] = -inf)
    int HI = n;    // invariant: a[HI] >= key  (a[n]  = +inf)
    while (HI - LO > 1) {
        const int w   = HI - LO;
        const int pos = LO + 1 + (int)(((long long)(w - 1) * lane) >> 6);
        const bool pred = a[pos] < key;
        const unsigned long long mask = __ballot(pred);
        if (mask == 0ull) { HI = LO + 1; break; }
        const int kmax = 63 - __clzll(mask);
        const int nLO  = LO + 1 + (int)(((long long)(w - 1) * kmax) >> 6);
        const int nHI  = (kmax < 63)
                       ? (LO + 1 + (int)(((long long)(w - 1) * (kmax + 1)) >> 6))
                       : HI;
        LO = nLO; HI = nHI;
    }
    return HI;
}

__global__ __launch_bounds__(NT) void fused_score_kernel(
    const float* __restrict__ x_src, const int* __restrict__ batch_src, int n_src,
    const float* __restrict__ x_tar, const int* __restrict__ batch_tar, int n_tar,
    float* __restrict__ out)
{
    __shared__ int   bounds[4];
    __shared__ float red[NW][DIM];   // 16 KB

    const int seg  = blockIdx.x;
    const int tid  = threadIdx.x;
    const int lane = tid & 63;
    const int w    = tid >> 6;       // wave id 0..15

    // waves 0..3 each find one boundary
    if (w < 4) {
        const int* arr = (w < 2) ? batch_src : batch_tar;
        const int  n   = (w < 2) ? n_src : n_tar;
        const int  lb  = lower_bound64(arr, n, seg + (w & 1), lane);
        if (lane == 0) bounds[w] = lb;
    }
    __syncthreads();
    const int s0 = bounds[0], s1 = bounds[1];
    const int t0 = bounds[2], t1 = bounds[3];

    // each wave streams rows s0+w, s0+w+16, ... ; lane owns cols [4l, 4l+4)
    float4 aS = make_float4(0.f, 0.f, 0.f, 0.f);
    float4 aT = make_float4(0.f, 0.f, 0.f, 0.f);
    const float* ps = x_src + (size_t)lane * 4;
    #pragma unroll 4
    for (int r = s0 + w; r < s1; r += NW) {
        const float4 v = *reinterpret_cast<const float4*>(ps + (size_t)r * DIM);
        aS.x += v.x; aS.y += v.y; aS.z += v.z; aS.w += v.w;
    }
    const float* pt = x_tar + (size_t)lane * 4;
    #pragma unroll 4
    for (int r = t0 + w; r < t1; r += NW) {
        const float4 v = *reinterpret_cast<const float4*>(pt + (size_t)r * DIM);
        aT.x += v.x; aT.y += v.y; aT.z += v.z; aT.w += v.w;
    }

    // cross-wave reduce src sums
    *reinterpret_cast<float4*>(&red[w][lane * 4]) = aS;
    __syncthreads();
    float sumS = 0.f, sumT = 0.f;
    if (tid < DIM) {
        #pragma unroll
        for (int i = 0; i < NW; ++i) sumS += red[i][tid];
    }
    __syncthreads();

    // cross-wave reduce tar sums (reuse LDS)
    *reinterpret_cast<float4*>(&red[w][lane * 4]) = aT;
    __syncthreads();
    if (tid < DIM) {
        #pragma unroll
        for (int i = 0; i < NW; ++i) sumT += red[i][tid];
        red[0][tid] = sumS * sumT;   // per-column products
    }
    __syncthreads();

    // wave 0: reduce 256 products -> dot, scale by 1/(cnt_src*cnt_tar)
    if (w == 0) {
        float d = red[0][lane] + red[0][lane + 64]
                + red[0][lane + 128] + red[0][lane + 192];
        #pragma unroll
        for (int off = 32; off > 0; off >>= 1)
            d += __shfl_down(d, off, 64);
        if (lane == 0) {
            const float c = (float)(s1 - s0) * (float)(t1 - t0);
            out[seg] = d / c;
        }
    }
}

extern "C" void kernel_launch(void* const* d_in, const int* in_sizes, int n_in,
                              void* d_out, int out_size, void* d_ws, size_t ws_size,
                              hipStream_t stream) {
    const float* x_src = (const float*)d_in[0];
    const int*   b_src = (const int*)  d_in[1];
    const float* x_tar = (const float*)d_in[2];
    const int*   b_tar = (const int*)  d_in[3];
    const int n_src = in_sizes[1];
    const int n_tar = in_sizes[3];
    float* out = (float*)d_out;

    fused_score_kernel<<<NSEG, NT, 0, stream>>>(
        x_src, b_src, n_src, x_tar, b_tar, n_tar, out);
}